// Round 1
// baseline (1071.952 us; speedup 1.0000x reference)
//
#include <hip/hip_runtime.h>

#define BATCH 2
#define SEQ   2048
#define DIM   1024
#define NH    16
#define DH    64

// ---------------- fp32 tiled GEMM: C[M,N] = A[M,K] @ B[K,N] (+bias) ----------
// 128x128 tile, BK=16, 256 threads, 8x8 micro-tile per thread.
template<bool BIAS>
__global__ __launch_bounds__(256)
void gemm_f32(const float* __restrict__ A, const float* __restrict__ B,
              const float* __restrict__ bias, float* __restrict__ C,
              int M, int N, int K)
{
    __shared__ float As[16][132];   // A tile stored transposed: As[k][m]
    __shared__ float Bs[16][132];   // Bs[k][n]

    const int t  = threadIdx.x;
    const int tx = t & 15;          // 0..15
    const int ty = t >> 4;          // 0..15
    const int m0 = blockIdx.y * 128;
    const int n0 = blockIdx.x * 128;

    float acc[8][8];
    #pragma unroll
    for (int i = 0; i < 8; i++)
        #pragma unroll
        for (int j = 0; j < 8; j++) acc[i][j] = 0.0f;

    for (int k0 = 0; k0 < K; k0 += 16) {
        // --- stage A tile (128 rows x 16 k), 2 float4 per thread, transpose ---
        #pragma unroll
        for (int i = 0; i < 2; i++) {
            int f   = t + i * 256;        // 0..511
            int row = f >> 2;             // 0..127
            int kc  = (f & 3) * 4;        // 0,4,8,12
            float4 v = *(const float4*)&A[(size_t)(m0 + row) * K + k0 + kc];
            As[kc + 0][row] = v.x;
            As[kc + 1][row] = v.y;
            As[kc + 2][row] = v.z;
            As[kc + 3][row] = v.w;
        }
        // --- stage B tile (16 k x 128 n), 2 float4 per thread ---
        #pragma unroll
        for (int i = 0; i < 2; i++) {
            int f  = t + i * 256;
            int kr = f >> 5;              // 0..15
            int nc = (f & 31) * 4;        // 0..124
            *(float4*)&Bs[kr][nc] = *(const float4*)&B[(size_t)(k0 + kr) * N + n0 + nc];
        }
        __syncthreads();

        #pragma unroll
        for (int k = 0; k < 16; k++) {
            float a[8], b[8];
            *(float4*)&a[0] = *(float4*)&As[k][ty * 8];
            *(float4*)&a[4] = *(float4*)&As[k][ty * 8 + 4];
            *(float4*)&b[0] = *(float4*)&Bs[k][tx * 8];
            *(float4*)&b[4] = *(float4*)&Bs[k][tx * 8 + 4];
            #pragma unroll
            for (int i = 0; i < 8; i++)
                #pragma unroll
                for (int j = 0; j < 8; j++)
                    acc[i][j] = fmaf(a[i], b[j], acc[i][j]);
        }
        __syncthreads();
    }

    #pragma unroll
    for (int i = 0; i < 8; i++) {
        int row = m0 + ty * 8 + i;
        #pragma unroll
        for (int j4 = 0; j4 < 2; j4++) {
            int col = n0 + tx * 8 + j4 * 4;
            float4 v;
            v.x = acc[i][j4 * 4 + 0];
            v.y = acc[i][j4 * 4 + 1];
            v.z = acc[i][j4 * 4 + 2];
            v.w = acc[i][j4 * 4 + 3];
            if (BIAS) {
                float4 bb = *(const float4*)&bias[col];
                v.x += bb.x; v.y += bb.y; v.z += bb.z; v.w += bb.w;
            }
            *(float4*)&C[(size_t)row * N + col] = v;
        }
    }
}

// ---------------- flash attention, fp32, Br=Bc=64, Dh=64 ---------------------
// qv: [B*N, 2048]  (q at col h*64+d, v at col 1024+h*64+d)
// kb: [B*N, 1024]
// xb: [B*N, 1024]  output in [B,N,H*Dh] layout (ready for proj GEMM)
__global__ __launch_bounds__(256)
void flash_attn(const float* __restrict__ qv, const float* __restrict__ kb,
                float* __restrict__ xb)
{
    __shared__ float Qt[DH][68];    // Q transposed: Qt[d][r]
    __shared__ float KPt[DH][68];   // K transposed Kt[d][c]; reused as Pt[c][r]
    __shared__ float Vs[64][68];    // Vs[c][d]

    const int t  = threadIdx.x;
    const int tx = t & 15;          // 0..15  (cols)
    const int ty = t >> 4;          // 0..15  (rows)
    const int qb = blockIdx.x;      // Q tile 0..31
    const int h  = blockIdx.y;      // head
    const int b  = blockIdx.z;      // batch
    const float scale = 0.125f;     // 64^-0.5

    const size_t rowbase = (size_t)b * SEQ;

    // --- load Q tile (64 rows x 64 d), transpose into LDS ---
    #pragma unroll
    for (int i = 0; i < 4; i++) {
        int f  = t + i * 256;            // 0..1023
        int r  = f >> 4;                 // 0..63
        int d4 = (f & 15) * 4;           // 0..60
        float4 v = *(const float4*)&qv[(rowbase + qb * 64 + r) * 2048 + h * 64 + d4];
        Qt[d4 + 0][r] = v.x;
        Qt[d4 + 1][r] = v.y;
        Qt[d4 + 2][r] = v.z;
        Qt[d4 + 3][r] = v.w;
    }

    float m_i[4], l_i[4], o[4][4];
    #pragma unroll
    for (int i = 0; i < 4; i++) {
        m_i[i] = -INFINITY;
        l_i[i] = 0.0f;
        #pragma unroll
        for (int j = 0; j < 4; j++) o[i][j] = 0.0f;
    }

    for (int kt = 0; kt < SEQ / 64; kt++) {
        __syncthreads();   // protect KPt/Vs from previous iteration's readers
        // --- load K tile (transposed) and V tile ---
        #pragma unroll
        for (int i = 0; i < 4; i++) {
            int f  = t + i * 256;
            int c  = f >> 4;
            int d4 = (f & 15) * 4;
            size_t n = rowbase + kt * 64 + c;
            float4 kv = *(const float4*)&kb[n * 1024 + h * 64 + d4];
            KPt[d4 + 0][c] = kv.x;
            KPt[d4 + 1][c] = kv.y;
            KPt[d4 + 2][c] = kv.z;
            KPt[d4 + 3][c] = kv.w;
            float4 vv = *(const float4*)&qv[n * 2048 + 1024 + h * 64 + d4];
            *(float4*)&Vs[c][d4] = vv;
        }
        __syncthreads();

        // --- S = Q K^T * scale   (rows ty*4.., cols tx*4..) ---
        float s[4][4];
        #pragma unroll
        for (int i = 0; i < 4; i++)
            #pragma unroll
            for (int j = 0; j < 4; j++) s[i][j] = 0.0f;

        #pragma unroll 8
        for (int d = 0; d < DH; d++) {
            float4 qa = *(float4*)&Qt[d][ty * 4];
            float4 ka = *(float4*)&KPt[d][tx * 4];
            float qr[4] = {qa.x, qa.y, qa.z, qa.w};
            float kc[4] = {ka.x, ka.y, ka.z, ka.w};
            #pragma unroll
            for (int i = 0; i < 4; i++)
                #pragma unroll
                for (int j = 0; j < 4; j++)
                    s[i][j] = fmaf(qr[i], kc[j], s[i][j]);
        }

        // --- online softmax update ---
        float p[4][4];
        float alpha[4];
        #pragma unroll
        for (int i = 0; i < 4; i++) {
            float mt = fmaxf(fmaxf(s[i][0], s[i][1]), fmaxf(s[i][2], s[i][3])) * scale;
            // reduce max across the 16 tx lanes (lane bits 0..3)
            #pragma unroll
            for (int mask = 1; mask < 16; mask <<= 1)
                mt = fmaxf(mt, __shfl_xor(mt, mask));
            float m_new = fmaxf(m_i[i], mt);
            alpha[i] = __expf(m_i[i] - m_new);
            float rs = 0.0f;
            #pragma unroll
            for (int j = 0; j < 4; j++) {
                p[i][j] = __expf(s[i][j] * scale - m_new);
                rs += p[i][j];
            }
            #pragma unroll
            for (int mask = 1; mask < 16; mask <<= 1)
                rs += __shfl_xor(rs, mask);
            l_i[i] = l_i[i] * alpha[i] + rs;
            m_i[i] = m_new;
            #pragma unroll
            for (int j = 0; j < 4; j++) o[i][j] *= alpha[i];
        }

        __syncthreads();   // everyone done reading KPt as K before P overwrite
        // --- write P transposed into KPt: Pt[key][row] ---
        #pragma unroll
        for (int i = 0; i < 4; i++)
            #pragma unroll
            for (int j = 0; j < 4; j++)
                KPt[tx * 4 + j][ty * 4 + i] = p[i][j];
        __syncthreads();

        // --- O += P @ V   (o cols are d = tx*4..) ---
        #pragma unroll 8
        for (int kk = 0; kk < 64; kk++) {
            float4 pp = *(float4*)&KPt[kk][ty * 4];
            float4 vv = *(float4*)&Vs[kk][tx * 4];
            float pr[4] = {pp.x, pp.y, pp.z, pp.w};
            float vc[4] = {vv.x, vv.y, vv.z, vv.w};
            #pragma unroll
            for (int i = 0; i < 4; i++)
                #pragma unroll
                for (int j = 0; j < 4; j++)
                    o[i][j] = fmaf(pr[i], vc[j], o[i][j]);
        }
    }

    // --- normalize and store x in [B,N,H*Dh] layout ---
    #pragma unroll
    for (int i = 0; i < 4; i++) {
        float rl = 1.0f / l_i[i];
        size_t row = rowbase + qb * 64 + ty * 4 + i;
        float4 v;
        v.x = o[i][0] * rl;
        v.y = o[i][1] * rl;
        v.z = o[i][2] * rl;
        v.w = o[i][3] * rl;
        *(float4*)&xb[row * 1024 + h * 64 + tx * 4] = v;
    }
}

extern "C" void kernel_launch(void* const* d_in, const int* in_sizes, int n_in,
                              void* d_out, int out_size, void* d_ws, size_t ws_size,
                              hipStream_t stream)
{
    const float* input_qv = (const float*)d_in[0];
    const float* input_k  = (const float*)d_in[1];
    const float* W_qv     = (const float*)d_in[2];
    const float* W_k      = (const float*)d_in[3];
    const float* W_proj   = (const float*)d_in[4];
    const float* b_proj   = (const float*)d_in[5];
    float* out = (float*)d_out;

    const int M = BATCH * SEQ;                       // 4096

    float* qv_buf = (float*)d_ws;                    // 4096 x 2048 = 33.5 MB
    float* x_buf  = qv_buf + (size_t)M * 2048;       // 4096 x 1024 = 16.8 MB
    float* k_buf  = out;                             // park k-proj in d_out (safe: fully
                                                     // rewritten by final GEMM, stream-ordered)

    dim3 blk(256);
    // 1) qv projection: [4096,1024] @ [1024,2048]
    gemm_f32<false><<<dim3(2048 / 128, M / 128), blk, 0, stream>>>(
        input_qv, W_qv, nullptr, qv_buf, M, 2048, 1024);
    // 2) k projection: [4096,1024] @ [1024,1024]
    gemm_f32<false><<<dim3(1024 / 128, M / 128), blk, 0, stream>>>(
        input_k, W_k, nullptr, k_buf, M, 1024, 1024);
    // 3) flash attention
    flash_attn<<<dim3(SEQ / 64, NH, BATCH), blk, 0, stream>>>(qv_buf, k_buf, x_buf);
    // 4) output projection + bias
    gemm_f32<true><<<dim3(1024 / 128, M / 128), blk, 0, stream>>>(
        x_buf, W_proj, b_proj, out, M, 1024, 1024);
}

// Round 2
// 800.353 us; speedup vs baseline: 1.3393x; 1.3393x over previous
//
#include <hip/hip_runtime.h>
#include <stdint.h>

#define BATCH 2
#define SEQ   2048
#define DIM   1024
#define NH    16
#define DH    64

// MFMA fragment carriers (guide §3: short8 = 8 bf16 = 4 VGPRs)
typedef short bf16x8 __attribute__((ext_vector_type(8)));
typedef float floatx4 __attribute__((ext_vector_type(4)));

// k-block XOR swizzle to spread LDS banks across the 16 rows of a fragment read
__device__ __forceinline__ int swz(int r) { return (r ^ (r >> 2)) & 3; }

// Split two fp32 into packed bf16 hi-pair and lo-pair (truncation split:
// a = hi + lo with |err| <= 2^-16 |a|; lo = bf16(a - float(hi)))
__device__ __forceinline__ void split2(float x0, float x1, uint32_t& hi, uint32_t& lo) {
    uint32_t u0 = __float_as_uint(x0), u1 = __float_as_uint(x1);
    uint32_t m0 = u0 & 0xFFFF0000u;
    uint32_t m1 = u1 & 0xFFFF0000u;
    hi = (u0 >> 16) | m1;
    float l0 = x0 - __uint_as_float(m0);
    float l1 = x1 - __uint_as_float(m1);
    lo = (__float_as_uint(l0) >> 16) | (__float_as_uint(l1) & 0xFFFF0000u);
}

// ---------------- bf16x3 MFMA GEMM: C[M,N] = A[M,K] @ B[K,N] (+bias), fp32 io
// 128x128 tile, BK=32, 256 thr = 4 waves, wave = 64x64 (4x4 frags of 16x16x32).
// A,B split to hi/lo bf16 during LDS staging; C = Ah*Bh + Ah*Bl + Al*Bh.
template<bool BIAS>
__global__ __launch_bounds__(256, 3)
void gemm_bf16x3(const float* __restrict__ A, const float* __restrict__ B,
                 const float* __restrict__ bias, float* __restrict__ C,
                 int M, int N, int K)
{
    // [row][k] bf16 packed as u32 pairs; row stride 16 u32 (32 bf16), k-block swizzled
    __shared__ uint32_t Ah[128 * 16], Al[128 * 16], Bh[128 * 16], Bl[128 * 16];

    const int t    = threadIdx.x;
    const int lane = t & 63;
    const int w    = t >> 6;
    const int wm   = w & 1, wn = w >> 1;
    const int quad = lane >> 4, l15 = lane & 15;
    const int m0 = blockIdx.y * 128, n0 = blockIdx.x * 128;

    // staging coordinates
    const int ar  = t >> 1;            // A row 0..127
    const int ab0 = (t & 1) * 2;       // A first k-block (0 or 2)
    const int as  = swz(ar);
    const int bc  = (t & 31) * 4;      // B n base 0..124
    const int bk  = (t >> 5) * 4;      // B k base 0..28
    const int bb  = bk >> 3;           // B k-block
    const int bp  = (bk & 7) >> 1;     // u32 offset within block (0 or 2)

    floatx4 acc[4][4];
    #pragma unroll
    for (int i = 0; i < 4; i++)
        #pragma unroll
        for (int j = 0; j < 4; j++)
            #pragma unroll
            for (int e = 0; e < 4; e++) acc[i][j][e] = 0.0f;

    for (int k0 = 0; k0 < K; k0 += 32) {
        if (k0) __syncthreads();
        // ---- stage A: row ar, 16 consecutive k, convert + split ----
        float f[16];
        #pragma unroll
        for (int i = 0; i < 4; i++)
            *(float4*)&f[i * 4] =
                *(const float4*)&A[(size_t)(m0 + ar) * K + k0 + ab0 * 8 + i * 4];
        uint32_t hi[8], lo[8];
        #pragma unroll
        for (int j = 0; j < 8; j++) split2(f[2 * j], f[2 * j + 1], hi[j], lo[j]);
        {
            int i0 = ar * 16 + ((ab0 ^ as) * 4);
            int i1 = ar * 16 + (((ab0 + 1) ^ as) * 4);
            *(uint4*)&Ah[i0] = make_uint4(hi[0], hi[1], hi[2], hi[3]);
            *(uint4*)&Ah[i1] = make_uint4(hi[4], hi[5], hi[6], hi[7]);
            *(uint4*)&Al[i0] = make_uint4(lo[0], lo[1], lo[2], lo[3]);
            *(uint4*)&Al[i1] = make_uint4(lo[4], lo[5], lo[6], lo[7]);
        }
        // ---- stage B: 4 k-rows x 4 n-cols, transpose to [n][k] + split ----
        float4 g[4];
        #pragma unroll
        for (int j = 0; j < 4; j++)
            g[j] = *(const float4*)&B[(size_t)(k0 + bk + j) * N + n0 + bc];
        #pragma unroll
        for (int nn = 0; nn < 4; nn++) {
            int n = bc + nn;
            float e0 = ((const float*)&g[0])[nn];
            float e1 = ((const float*)&g[1])[nn];
            float e2 = ((const float*)&g[2])[nn];
            float e3 = ((const float*)&g[3])[nn];
            uint32_t h0, q0, h1, q1;
            split2(e0, e1, h0, q0);
            split2(e2, e3, h1, q1);
            int bi = n * 16 + ((bb ^ swz(n)) * 4) + bp;
            *(uint2*)&Bh[bi] = make_uint2(h0, h1);
            *(uint2*)&Bl[bi] = make_uint2(q0, q1);
        }
        __syncthreads();

        // ---- fragments + MFMA ----
        bf16x8 vbh[4], vbl[4];
        #pragma unroll
        for (int fn = 0; fn < 4; fn++) {
            int br = wn * 64 + fn * 16 + l15;
            int bi = br * 16 + ((quad ^ swz(br)) * 4);
            vbh[fn] = *(const bf16x8*)&Bh[bi];
            vbl[fn] = *(const bf16x8*)&Bl[bi];
        }
        #pragma unroll
        for (int fm = 0; fm < 4; fm++) {
            int arow = wm * 64 + fm * 16 + l15;
            int ai = arow * 16 + ((quad ^ swz(arow)) * 4);
            bf16x8 vah = *(const bf16x8*)&Ah[ai];
            bf16x8 val = *(const bf16x8*)&Al[ai];
            #pragma unroll
            for (int fn = 0; fn < 4; fn++) {
                acc[fm][fn] = __builtin_amdgcn_mfma_f32_16x16x32_bf16(vah, vbh[fn], acc[fm][fn], 0, 0, 0);
                acc[fm][fn] = __builtin_amdgcn_mfma_f32_16x16x32_bf16(vah, vbl[fn], acc[fm][fn], 0, 0, 0);
                acc[fm][fn] = __builtin_amdgcn_mfma_f32_16x16x32_bf16(val, vbh[fn], acc[fm][fn], 0, 0, 0);
            }
        }
    }

    // ---- epilogue: C/D layout col=lane&15, row=quad*4+reg (m89-verified) ----
    #pragma unroll
    for (int fn = 0; fn < 4; fn++) {
        int col = n0 + wn * 64 + fn * 16 + l15;
        float bv = BIAS ? bias[col] : 0.0f;
        #pragma unroll
        for (int fm = 0; fm < 4; fm++) {
            int row = m0 + wm * 64 + fm * 16 + quad * 4;
            #pragma unroll
            for (int r = 0; r < 4; r++)
                C[(size_t)(row + r) * N + col] = acc[fm][fn][r] + bv;
        }
    }
}

// ---------------- flash attention, fp32, Br=Bc=64, Dh=64 (unchanged R1) -----
__global__ __launch_bounds__(256)
void flash_attn(const float* __restrict__ qv, const float* __restrict__ kb,
                float* __restrict__ xb)
{
    __shared__ float Qt[DH][68];    // Q transposed: Qt[d][r]
    __shared__ float KPt[DH][68];   // K transposed Kt[d][c]; reused as Pt[c][r]
    __shared__ float Vs[64][68];    // Vs[c][d]

    const int t  = threadIdx.x;
    const int tx = t & 15;
    const int ty = t >> 4;
    const int qb = blockIdx.x;
    const int h  = blockIdx.y;
    const int b  = blockIdx.z;
    const float scale = 0.125f;

    const size_t rowbase = (size_t)b * SEQ;

    #pragma unroll
    for (int i = 0; i < 4; i++) {
        int f  = t + i * 256;
        int r  = f >> 4;
        int d4 = (f & 15) * 4;
        float4 v = *(const float4*)&qv[(rowbase + qb * 64 + r) * 2048 + h * 64 + d4];
        Qt[d4 + 0][r] = v.x;
        Qt[d4 + 1][r] = v.y;
        Qt[d4 + 2][r] = v.z;
        Qt[d4 + 3][r] = v.w;
    }

    float m_i[4], l_i[4], o[4][4];
    #pragma unroll
    for (int i = 0; i < 4; i++) {
        m_i[i] = -INFINITY;
        l_i[i] = 0.0f;
        #pragma unroll
        for (int j = 0; j < 4; j++) o[i][j] = 0.0f;
    }

    for (int kt = 0; kt < SEQ / 64; kt++) {
        __syncthreads();
        #pragma unroll
        for (int i = 0; i < 4; i++) {
            int f  = t + i * 256;
            int c  = f >> 4;
            int d4 = (f & 15) * 4;
            size_t n = rowbase + kt * 64 + c;
            float4 kv = *(const float4*)&kb[n * 1024 + h * 64 + d4];
            KPt[d4 + 0][c] = kv.x;
            KPt[d4 + 1][c] = kv.y;
            KPt[d4 + 2][c] = kv.z;
            KPt[d4 + 3][c] = kv.w;
            float4 vv = *(const float4*)&qv[n * 2048 + 1024 + h * 64 + d4];
            *(float4*)&Vs[c][d4] = vv;
        }
        __syncthreads();

        float s[4][4];
        #pragma unroll
        for (int i = 0; i < 4; i++)
            #pragma unroll
            for (int j = 0; j < 4; j++) s[i][j] = 0.0f;

        #pragma unroll 8
        for (int d = 0; d < DH; d++) {
            float4 qa = *(float4*)&Qt[d][ty * 4];
            float4 ka = *(float4*)&KPt[d][tx * 4];
            float qr[4] = {qa.x, qa.y, qa.z, qa.w};
            float kc[4] = {ka.x, ka.y, ka.z, ka.w};
            #pragma unroll
            for (int i = 0; i < 4; i++)
                #pragma unroll
                for (int j = 0; j < 4; j++)
                    s[i][j] = fmaf(qr[i], kc[j], s[i][j]);
        }

        float p[4][4];
        float alpha[4];
        #pragma unroll
        for (int i = 0; i < 4; i++) {
            float mt = fmaxf(fmaxf(s[i][0], s[i][1]), fmaxf(s[i][2], s[i][3])) * scale;
            #pragma unroll
            for (int mask = 1; mask < 16; mask <<= 1)
                mt = fmaxf(mt, __shfl_xor(mt, mask));
            float m_new = fmaxf(m_i[i], mt);
            alpha[i] = __expf(m_i[i] - m_new);
            float rs = 0.0f;
            #pragma unroll
            for (int j = 0; j < 4; j++) {
                p[i][j] = __expf(s[i][j] * scale - m_new);
                rs += p[i][j];
            }
            #pragma unroll
            for (int mask = 1; mask < 16; mask <<= 1)
                rs += __shfl_xor(rs, mask);
            l_i[i] = l_i[i] * alpha[i] + rs;
            m_i[i] = m_new;
            #pragma unroll
            for (int j = 0; j < 4; j++) o[i][j] *= alpha[i];
        }

        __syncthreads();
        #pragma unroll
        for (int i = 0; i < 4; i++)
            #pragma unroll
            for (int j = 0; j < 4; j++)
                KPt[tx * 4 + j][ty * 4 + i] = p[i][j];
        __syncthreads();

        #pragma unroll 8
        for (int kk = 0; kk < 64; kk++) {
            float4 pp = *(float4*)&KPt[kk][ty * 4];
            float4 vv = *(float4*)&Vs[kk][tx * 4];
            float pr[4] = {pp.x, pp.y, pp.z, pp.w};
            float vc[4] = {vv.x, vv.y, vv.z, vv.w};
            #pragma unroll
            for (int i = 0; i < 4; i++)
                #pragma unroll
                for (int j = 0; j < 4; j++)
                    o[i][j] = fmaf(pr[i], vc[j], o[i][j]);
        }
    }

    #pragma unroll
    for (int i = 0; i < 4; i++) {
        float rl = 1.0f / l_i[i];
        size_t row = rowbase + qb * 64 + ty * 4 + i;
        float4 v;
        v.x = o[i][0] * rl;
        v.y = o[i][1] * rl;
        v.z = o[i][2] * rl;
        v.w = o[i][3] * rl;
        *(float4*)&xb[row * 1024 + h * 64 + tx * 4] = v;
    }
}

extern "C" void kernel_launch(void* const* d_in, const int* in_sizes, int n_in,
                              void* d_out, int out_size, void* d_ws, size_t ws_size,
                              hipStream_t stream)
{
    const float* input_qv = (const float*)d_in[0];
    const float* input_k  = (const float*)d_in[1];
    const float* W_qv     = (const float*)d_in[2];
    const float* W_k      = (const float*)d_in[3];
    const float* W_proj   = (const float*)d_in[4];
    const float* b_proj   = (const float*)d_in[5];
    float* out = (float*)d_out;

    const int M = BATCH * SEQ;                       // 4096

    float* qv_buf = (float*)d_ws;                    // 4096 x 2048 fp32 = 33.5 MB
    float* x_buf  = qv_buf + (size_t)M * 2048;       // 4096 x 1024 fp32 = 16.8 MB
    float* k_buf  = out;                             // park k-proj in d_out (rewritten by
                                                     // final GEMM, stream-ordered)

    dim3 blk(256);
    // 1) qv projection: [4096,1024] @ [1024,2048]
    gemm_bf16x3<false><<<dim3(2048 / 128, M / 128), blk, 0, stream>>>(
        input_qv, W_qv, nullptr, qv_buf, M, 2048, 1024);
    // 2) k projection: [4096,1024] @ [1024,1024]
    gemm_bf16x3<false><<<dim3(1024 / 128, M / 128), blk, 0, stream>>>(
        input_k, W_k, nullptr, k_buf, M, 1024, 1024);
    // 3) flash attention (fp32, unchanged)
    flash_attn<<<dim3(SEQ / 64, NH, BATCH), blk, 0, stream>>>(qv_buf, k_buf, x_buf);
    // 4) output projection + bias
    gemm_bf16x3<true><<<dim3(1024 / 128, M / 128), blk, 0, stream>>>(
        x_buf, W_proj, b_proj, out, M, 1024, 1024);
}

// Round 3
// 447.776 us; speedup vs baseline: 2.3939x; 1.7874x over previous
//
#include <hip/hip_runtime.h>
#include <stdint.h>

#define BATCH 2
#define SEQ   2048
#define DIM   1024
#define NH    16
#define DH    64

// MFMA fragment carriers (guide §3: short8 = 8 bf16 = 4 VGPRs)
typedef short bf16x8 __attribute__((ext_vector_type(8)));
typedef float floatx4 __attribute__((ext_vector_type(4)));

// k-block XOR swizzle (GEMM staging)
__device__ __forceinline__ int swz(int r) { return (r ^ (r >> 2)) & 3; }

// Split two fp32 into packed bf16 hi-pair and lo-pair (truncation split:
// a = hi + lo exactly to ~2^-17 rel; lo = bf16(a - float(hi)))
__device__ __forceinline__ void split2(float x0, float x1, uint32_t& hi, uint32_t& lo) {
    uint32_t u0 = __float_as_uint(x0), u1 = __float_as_uint(x1);
    uint32_t m0 = u0 & 0xFFFF0000u;
    uint32_t m1 = u1 & 0xFFFF0000u;
    hi = (u0 >> 16) | m1;
    float l0 = x0 - __uint_as_float(m0);
    float l1 = x1 - __uint_as_float(m1);
    lo = (__float_as_uint(l0) >> 16) | (__float_as_uint(l1) & 0xFFFF0000u);
}

// pack two fp32 to bf16 pair with round-to-nearest-even
__device__ __forceinline__ uint32_t pack_bf16_rne(float x0, float x1) {
    uint32_t u0 = __float_as_uint(x0), u1 = __float_as_uint(x1);
    u0 += 0x7FFFu + ((u0 >> 16) & 1);
    u1 += 0x7FFFu + ((u1 >> 16) & 1);
    return (u0 >> 16) | (u1 & 0xFFFF0000u);
}

// ---------------- bf16x3 MFMA GEMM (unchanged from R2, verified) ------------
template<bool BIAS>
__global__ __launch_bounds__(256, 3)
void gemm_bf16x3(const float* __restrict__ A, const float* __restrict__ B,
                 const float* __restrict__ bias, float* __restrict__ C,
                 int M, int N, int K)
{
    __shared__ uint32_t Ah[128 * 16], Al[128 * 16], Bh[128 * 16], Bl[128 * 16];

    const int t    = threadIdx.x;
    const int lane = t & 63;
    const int w    = t >> 6;
    const int wm   = w & 1, wn = w >> 1;
    const int quad = lane >> 4, l15 = lane & 15;
    const int m0 = blockIdx.y * 128, n0 = blockIdx.x * 128;

    const int ar  = t >> 1;
    const int ab0 = (t & 1) * 2;
    const int as  = swz(ar);
    const int bc  = (t & 31) * 4;
    const int bk  = (t >> 5) * 4;
    const int bb  = bk >> 3;
    const int bp  = (bk & 7) >> 1;

    floatx4 acc[4][4];
    #pragma unroll
    for (int i = 0; i < 4; i++)
        #pragma unroll
        for (int j = 0; j < 4; j++)
            #pragma unroll
            for (int e = 0; e < 4; e++) acc[i][j][e] = 0.0f;

    for (int k0 = 0; k0 < K; k0 += 32) {
        if (k0) __syncthreads();
        float f[16];
        #pragma unroll
        for (int i = 0; i < 4; i++)
            *(float4*)&f[i * 4] =
                *(const float4*)&A[(size_t)(m0 + ar) * K + k0 + ab0 * 8 + i * 4];
        uint32_t hi[8], lo[8];
        #pragma unroll
        for (int j = 0; j < 8; j++) split2(f[2 * j], f[2 * j + 1], hi[j], lo[j]);
        {
            int i0 = ar * 16 + ((ab0 ^ as) * 4);
            int i1 = ar * 16 + (((ab0 + 1) ^ as) * 4);
            *(uint4*)&Ah[i0] = make_uint4(hi[0], hi[1], hi[2], hi[3]);
            *(uint4*)&Ah[i1] = make_uint4(hi[4], hi[5], hi[6], hi[7]);
            *(uint4*)&Al[i0] = make_uint4(lo[0], lo[1], lo[2], lo[3]);
            *(uint4*)&Al[i1] = make_uint4(lo[4], lo[5], lo[6], lo[7]);
        }
        float4 g[4];
        #pragma unroll
        for (int j = 0; j < 4; j++)
            g[j] = *(const float4*)&B[(size_t)(k0 + bk + j) * N + n0 + bc];
        #pragma unroll
        for (int nn = 0; nn < 4; nn++) {
            int n = bc + nn;
            float e0 = ((const float*)&g[0])[nn];
            float e1 = ((const float*)&g[1])[nn];
            float e2 = ((const float*)&g[2])[nn];
            float e3 = ((const float*)&g[3])[nn];
            uint32_t h0, q0, h1, q1;
            split2(e0, e1, h0, q0);
            split2(e2, e3, h1, q1);
            int bi = n * 16 + ((bb ^ swz(n)) * 4) + bp;
            *(uint2*)&Bh[bi] = make_uint2(h0, h1);
            *(uint2*)&Bl[bi] = make_uint2(q0, q1);
        }
        __syncthreads();

        bf16x8 vbh[4], vbl[4];
        #pragma unroll
        for (int fn = 0; fn < 4; fn++) {
            int br = wn * 64 + fn * 16 + l15;
            int bi = br * 16 + ((quad ^ swz(br)) * 4);
            vbh[fn] = *(const bf16x8*)&Bh[bi];
            vbl[fn] = *(const bf16x8*)&Bl[bi];
        }
        #pragma unroll
        for (int fm = 0; fm < 4; fm++) {
            int arow = wm * 64 + fm * 16 + l15;
            int ai = arow * 16 + ((quad ^ swz(arow)) * 4);
            bf16x8 vah = *(const bf16x8*)&Ah[ai];
            bf16x8 val = *(const bf16x8*)&Al[ai];
            #pragma unroll
            for (int fn = 0; fn < 4; fn++) {
                acc[fm][fn] = __builtin_amdgcn_mfma_f32_16x16x32_bf16(vah, vbh[fn], acc[fm][fn], 0, 0, 0);
                acc[fm][fn] = __builtin_amdgcn_mfma_f32_16x16x32_bf16(vah, vbl[fn], acc[fm][fn], 0, 0, 0);
                acc[fm][fn] = __builtin_amdgcn_mfma_f32_16x16x32_bf16(val, vbh[fn], acc[fm][fn], 0, 0, 0);
            }
        }
    }

    #pragma unroll
    for (int fn = 0; fn < 4; fn++) {
        int col = n0 + wn * 64 + fn * 16 + l15;
        float bv = BIAS ? bias[col] : 0.0f;
        #pragma unroll
        for (int fm = 0; fm < 4; fm++) {
            int row = m0 + wm * 64 + fm * 16 + quad * 4;
            #pragma unroll
            for (int r = 0; r < 4; r++)
                C[(size_t)(row + r) * N + col] = acc[fm][fn][r] + bv;
        }
    }
}

// ---------------- MFMA flash attention -------------------------------------
// Br=Bc=64. 4 waves, wave w owns Q rows w*16..w*16+15.
// S^T = K·Q^T via 16x16x32 bf16x3 (m=key, n=qrow) -> one qrow per lane (col=l15),
// online softmax scalar-per-lane, P -> LDS [qrow][key] (own rows only, no barrier),
// O^T = Vt·P^T (m=d, n=qrow), plain bf16 PV.
// Row stride 36 u32 (144 B): b128 frag reads land 2 lanes/bank (free, m136).
#define FSTR 36
__global__ __launch_bounds__(256, 2)
void flash_attn(const float* __restrict__ qv, const float* __restrict__ kb,
                float* __restrict__ xb)
{
    __shared__ uint32_t Qh[64 * FSTR], Ql[64 * FSTR];
    __shared__ uint32_t Kh[64 * FSTR], Kl[64 * FSTR];
    __shared__ uint32_t Vt[64 * FSTR];          // Vt[d][key], plain bf16
    __shared__ uint32_t Pt[64 * FSTR];          // P[qrow][key], plain bf16

    const int t    = threadIdx.x;
    const int lane = t & 63;
    const int w    = t >> 6;
    const int quad = lane >> 4, l15 = lane & 15;
    const int qb = blockIdx.x;
    const int h  = blockIdx.y;
    const int b  = blockIdx.z;
    const float scale = 0.125f;

    const size_t rowbase = (size_t)b * SEQ;
    const int qrow = w * 16 + l15;              // this lane's Q row (0..63)

    // ---- stage Q tile once: [row][d] hi/lo, coalesced 16-float rows ----
    {
        int row = t >> 2;                       // 0..63
        int d0  = (t & 3) * 16;                 // 0,16,32,48
        const float* src = &qv[(rowbase + qb * 64 + row) * 2048 + h * 64 + d0];
        float f[16];
        #pragma unroll
        for (int i = 0; i < 4; i++) *(float4*)&f[i * 4] = *(const float4*)&src[i * 4];
        uint32_t hi[8], lo[8];
        #pragma unroll
        for (int j = 0; j < 8; j++) split2(f[2 * j], f[2 * j + 1], hi[j], lo[j]);
        int i0 = row * FSTR + d0 / 2;
        *(uint4*)&Qh[i0]     = make_uint4(hi[0], hi[1], hi[2], hi[3]);
        *(uint4*)&Qh[i0 + 4] = make_uint4(hi[4], hi[5], hi[6], hi[7]);
        *(uint4*)&Ql[i0]     = make_uint4(lo[0], lo[1], lo[2], lo[3]);
        *(uint4*)&Ql[i0 + 4] = make_uint4(lo[4], lo[5], lo[6], lo[7]);
    }

    float m_i = -INFINITY, l_i = 0.0f;
    floatx4 acc_o[4];
    #pragma unroll
    for (int fm = 0; fm < 4; fm++)
        #pragma unroll
        for (int e = 0; e < 4; e++) acc_o[fm][e] = 0.0f;

    for (int kt = 0; kt < SEQ / 64; kt++) {
        __syncthreads();   // prev iter's readers done with Kh/Kl/Vt (also orders Q staging)
        // ---- stage K tile [key][d] hi/lo ----
        {
            int row = t >> 2;
            int d0  = (t & 3) * 16;
            const float* src = &kb[(rowbase + kt * 64 + row) * 1024 + h * 64 + d0];
            float f[16];
            #pragma unroll
            for (int i = 0; i < 4; i++) *(float4*)&f[i * 4] = *(const float4*)&src[i * 4];
            uint32_t hi[8], lo[8];
            #pragma unroll
            for (int j = 0; j < 8; j++) split2(f[2 * j], f[2 * j + 1], hi[j], lo[j]);
            int i0 = row * FSTR + d0 / 2;
            *(uint4*)&Kh[i0]     = make_uint4(hi[0], hi[1], hi[2], hi[3]);
            *(uint4*)&Kh[i0 + 4] = make_uint4(hi[4], hi[5], hi[6], hi[7]);
            *(uint4*)&Kl[i0]     = make_uint4(lo[0], lo[1], lo[2], lo[3]);
            *(uint4*)&Kl[i0 + 4] = make_uint4(lo[4], lo[5], lo[6], lo[7]);
        }
        // ---- stage V tile transposed: Vt[d][key], plain bf16 RNE ----
        {
            int key0 = (t & 15) * 4;            // 0..60
            int d0   = (t >> 4) * 4;            // 0..60
            const float* src = &qv[(rowbase + kt * 64 + key0) * 2048 + 1024 + h * 64 + d0];
            float4 r0 = *(const float4*)&src[0 * 2048];
            float4 r1 = *(const float4*)&src[1 * 2048];
            float4 r2 = *(const float4*)&src[2 * 2048];
            float4 r3 = *(const float4*)&src[3 * 2048];
            const float* p0 = (const float*)&r0;
            const float* p1 = (const float*)&r1;
            const float* p2 = (const float*)&r2;
            const float* p3 = (const float*)&r3;
            #pragma unroll
            for (int j = 0; j < 4; j++) {
                uint32_t a = pack_bf16_rne(p0[j], p1[j]);
                uint32_t c = pack_bf16_rne(p2[j], p3[j]);
                *(uint2*)&Vt[(d0 + j) * FSTR + key0 / 2] = make_uint2(a, c);
            }
        }
        __syncthreads();

        // ---- S^T = K·Q^T (bf16x3): m-frag fm = keys fm*16.., n = this wave's 16 qrows
        floatx4 sacc[4];
        #pragma unroll
        for (int fm = 0; fm < 4; fm++)
            #pragma unroll
            for (int e = 0; e < 4; e++) sacc[fm][e] = 0.0f;

        #pragma unroll
        for (int s = 0; s < 2; s++) {
            int qi = qrow * FSTR + s * 16 + quad * 4;
            bf16x8 vqh = *(const bf16x8*)&Qh[qi];
            bf16x8 vql = *(const bf16x8*)&Ql[qi];
            #pragma unroll
            for (int fm = 0; fm < 4; fm++) {
                int ki = (fm * 16 + l15) * FSTR + s * 16 + quad * 4;
                bf16x8 vkh = *(const bf16x8*)&Kh[ki];
                bf16x8 vkl = *(const bf16x8*)&Kl[ki];
                sacc[fm] = __builtin_amdgcn_mfma_f32_16x16x32_bf16(vkh, vqh, sacc[fm], 0, 0, 0);
                sacc[fm] = __builtin_amdgcn_mfma_f32_16x16x32_bf16(vkh, vql, sacc[fm], 0, 0, 0);
                sacc[fm] = __builtin_amdgcn_mfma_f32_16x16x32_bf16(vkl, vqh, sacc[fm], 0, 0, 0);
            }
        }

        // ---- online softmax: one qrow per lane; keys = fm*16 + quad*4 + r ----
        float p[4][4];
        float mt = -INFINITY;
        #pragma unroll
        for (int fm = 0; fm < 4; fm++)
            #pragma unroll
            for (int r = 0; r < 4; r++) {
                p[fm][r] = sacc[fm][r] * scale;
                mt = fmaxf(mt, p[fm][r]);
            }
        mt = fmaxf(mt, __shfl_xor(mt, 16));
        mt = fmaxf(mt, __shfl_xor(mt, 32));
        float m_new = fmaxf(m_i, mt);
        float alpha = __expf(m_i - m_new);
        float rs = 0.0f;
        #pragma unroll
        for (int fm = 0; fm < 4; fm++)
            #pragma unroll
            for (int r = 0; r < 4; r++) {
                p[fm][r] = __expf(p[fm][r] - m_new);
                rs += p[fm][r];
            }
        rs += __shfl_xor(rs, 16);
        rs += __shfl_xor(rs, 32);
        l_i = l_i * alpha + rs;
        m_i = m_new;
        #pragma unroll
        for (int fm = 0; fm < 4; fm++)
            #pragma unroll
            for (int e = 0; e < 4; e++) acc_o[fm][e] *= alpha;

        // ---- P -> LDS [qrow][key] (this wave's own rows; no barrier needed) ----
        #pragma unroll
        for (int fm = 0; fm < 4; fm++) {
            uint32_t u0 = pack_bf16_rne(p[fm][0], p[fm][1]);
            uint32_t u1 = pack_bf16_rne(p[fm][2], p[fm][3]);
            *(uint2*)&Pt[qrow * FSTR + fm * 8 + quad * 2] = make_uint2(u0, u1);
        }

        // ---- O^T += Vt · P^T : m-frag fm = d fm*16.., n = 16 qrows, k = 64 keys
        #pragma unroll
        for (int s = 0; s < 2; s++) {
            bf16x8 pb = *(const bf16x8*)&Pt[qrow * FSTR + s * 16 + quad * 4];
            #pragma unroll
            for (int fm = 0; fm < 4; fm++) {
                bf16x8 va = *(const bf16x8*)&Vt[(fm * 16 + l15) * FSTR + s * 16 + quad * 4];
                acc_o[fm] = __builtin_amdgcn_mfma_f32_16x16x32_bf16(va, pb, acc_o[fm], 0, 0, 0);
            }
        }
    }

    // ---- epilogue: O^T[d][qrow] / l -> xb[row][h*64+d], contiguous float4 ----
    float rl = 1.0f / l_i;
    size_t row = rowbase + qb * 64 + qrow;
    #pragma unroll
    for (int fm = 0; fm < 4; fm++) {
        int d0 = fm * 16 + quad * 4;
        float4 v;
        v.x = acc_o[fm][0] * rl;
        v.y = acc_o[fm][1] * rl;
        v.z = acc_o[fm][2] * rl;
        v.w = acc_o[fm][3] * rl;
        *(float4*)&xb[row * 1024 + h * 64 + d0] = v;
    }
}

extern "C" void kernel_launch(void* const* d_in, const int* in_sizes, int n_in,
                              void* d_out, int out_size, void* d_ws, size_t ws_size,
                              hipStream_t stream)
{
    const float* input_qv = (const float*)d_in[0];
    const float* input_k  = (const float*)d_in[1];
    const float* W_qv     = (const float*)d_in[2];
    const float* W_k      = (const float*)d_in[3];
    const float* W_proj   = (const float*)d_in[4];
    const float* b_proj   = (const float*)d_in[5];
    float* out = (float*)d_out;

    const int M = BATCH * SEQ;                       // 4096

    float* qv_buf = (float*)d_ws;                    // 4096 x 2048 fp32 = 33.5 MB
    float* x_buf  = qv_buf + (size_t)M * 2048;       // 4096 x 1024 fp32 = 16.8 MB
    float* k_buf  = out;                             // park k-proj in d_out (rewritten by
                                                     // final GEMM, stream-ordered)

    dim3 blk(256);
    gemm_bf16x3<false><<<dim3(2048 / 128, M / 128), blk, 0, stream>>>(
        input_qv, W_qv, nullptr, qv_buf, M, 2048, 1024);
    gemm_bf16x3<false><<<dim3(1024 / 128, M / 128), blk, 0, stream>>>(
        input_k, W_k, nullptr, k_buf, M, 1024, 1024);
    flash_attn<<<dim3(SEQ / 64, NH, BATCH), blk, 0, stream>>>(qv_buf, k_buf, x_buf);
    gemm_bf16x3<true><<<dim3(1024 / 128, M / 128), blk, 0, stream>>>(
        x_buf, W_proj, b_proj, out, M, 1024, 1024);
}

// Round 4
// 411.554 us; speedup vs baseline: 2.6046x; 1.0880x over previous
//
#include <hip/hip_runtime.h>
#include <stdint.h>

#define BATCH 2
#define SEQ   2048
#define DIM   1024
#define NH    16
#define DH    64

typedef short bf16x8 __attribute__((ext_vector_type(8)));
typedef float floatx4 __attribute__((ext_vector_type(4)));

__device__ __forceinline__ int swz(int r) { return (r ^ (r >> 2)) & 3; }

// Split two fp32 into packed bf16 hi-pair and lo-pair (truncation split)
__device__ __forceinline__ void split2(float x0, float x1, uint32_t& hi, uint32_t& lo) {
    uint32_t u0 = __float_as_uint(x0), u1 = __float_as_uint(x1);
    uint32_t m0 = u0 & 0xFFFF0000u;
    uint32_t m1 = u1 & 0xFFFF0000u;
    hi = (u0 >> 16) | m1;
    float l0 = x0 - __uint_as_float(m0);
    float l1 = x1 - __uint_as_float(m1);
    lo = (__float_as_uint(l0) >> 16) | (__float_as_uint(l1) & 0xFFFF0000u);
}

__device__ __forceinline__ uint32_t pack_bf16_rne(float x0, float x1) {
    uint32_t u0 = __float_as_uint(x0), u1 = __float_as_uint(x1);
    u0 += 0x7FFFu + ((u0 >> 16) & 1);
    u1 += 0x7FFFu + ((u1 >> 16) & 1);
    return (u0 >> 16) | (u1 & 0xFFFF0000u);
}

// ---------------- one-time weight convert: fp32 [K][N] -> bf16 h/l [N][K] ---
// grid (64, 16): x<32 -> W_qv (N=2048), x<48 -> W_k, else W_proj. K=1024 all.
__global__ __launch_bounds__(256)
void convert_w(const float* __restrict__ Wqv, const float* __restrict__ Wk,
               const float* __restrict__ Wp,
               uint32_t* __restrict__ w1h, uint32_t* __restrict__ w1l,
               uint32_t* __restrict__ w2h, uint32_t* __restrict__ w2l,
               uint32_t* __restrict__ w3h, uint32_t* __restrict__ w3l)
{
    __shared__ ushort Lh[64][68], Ll[64][68];
    const int bx = blockIdx.x;
    const int k0 = blockIdx.y * 64;
    const float* src; uint32_t *dh, *dl; int N, n0;
    if (bx < 32)      { src = Wqv; dh = w1h; dl = w1l; N = 2048; n0 = bx * 64; }
    else if (bx < 48) { src = Wk;  dh = w2h; dl = w2l; N = 1024; n0 = (bx - 32) * 64; }
    else              { src = Wp;  dh = w3h; dl = w3l; N = 1024; n0 = (bx - 48) * 64; }
    const int t = threadIdx.x;
    const int n4 = (t & 15) * 4, kr = t >> 4;
    #pragma unroll
    for (int it = 0; it < 4; it++) {
        int k = kr + it * 16;
        float4 f = *(const float4*)&src[(size_t)(k0 + k) * N + n0 + n4];
        float ff[4] = {f.x, f.y, f.z, f.w};
        #pragma unroll
        for (int j = 0; j < 4; j++) {
            uint32_t u = __float_as_uint(ff[j]);
            uint32_t m = u & 0xFFFF0000u;
            Lh[k][n4 + j] = (ushort)(u >> 16);
            float lo = ff[j] - __uint_as_float(m);
            Ll[k][n4 + j] = (ushort)(__float_as_uint(lo) >> 16);
        }
    }
    __syncthreads();
    const int n = t >> 2, wk = (t & 3) * 8;
    uint32_t oh[8], ol[8];
    #pragma unroll
    for (int w = 0; w < 8; w++) {
        int kk = 2 * (wk + w);
        oh[w] = (uint32_t)Lh[kk][n] | ((uint32_t)Lh[kk + 1][n] << 16);
        ol[w] = (uint32_t)Ll[kk][n] | ((uint32_t)Ll[kk + 1][n] << 16);
    }
    size_t dst = (size_t)(n0 + n) * 512 + (k0 >> 1) + wk;
    *(uint4*)&dh[dst]     = make_uint4(oh[0], oh[1], oh[2], oh[3]);
    *(uint4*)&dh[dst + 4] = make_uint4(oh[4], oh[5], oh[6], oh[7]);
    *(uint4*)&dl[dst]     = make_uint4(ol[0], ol[1], ol[2], ol[3]);
    *(uint4*)&dl[dst + 4] = make_uint4(ol[4], ol[5], ol[6], ol[7]);
}

// ---------------- bf16x3 MFMA GEMM, swapped-operand (lane = C-row) ----------
// AMODE: 0 = fp32 A, split in staging; 1 = pre-split bf16 A (h/l, [M][K/2] words)
// BMODE: 0 = fp32 B [K][N], transpose+split in staging; 1 = pre-split bf16 B^T [N][K/2]
// EPI:   0 = fp32 + bias -> Cf; 1 = qv (cols<1024 -> O1h/O1l split, else O2 bf16-rne);
//        2 = O1h/O1l split
template<int AMODE, int BMODE, int EPI>
__global__ __launch_bounds__(256, 3)
void gemm_k(const float* __restrict__ Af,
            const uint32_t* __restrict__ Ahg, const uint32_t* __restrict__ Alg,
            const float* __restrict__ Bf,
            const uint32_t* __restrict__ Bth, const uint32_t* __restrict__ Btl,
            const float* __restrict__ bias, float* __restrict__ Cf,
            uint32_t* __restrict__ O1h, uint32_t* __restrict__ O1l,
            uint32_t* __restrict__ O2,
            int M, int N, int K)
{
    __shared__ uint32_t Ah[128 * 16], Al[128 * 16], Bh[128 * 16], Bl[128 * 16];

    const int t    = threadIdx.x;
    const int lane = t & 63;
    const int w    = t >> 6;
    const int wm   = w & 1, wn = w >> 1;
    const int quad = lane >> 4, l15 = lane & 15;
    const int m0 = blockIdx.y * 128, n0 = blockIdx.x * 128;
    const int Kw = K >> 1;

    // fp32-A staging coords
    const int ar  = t >> 1;
    const int ab0 = (t & 1) * 2;
    const int as  = swz(ar);
    // fp32-B staging coords
    const int bc  = (t & 31) * 4;
    const int bk  = (t >> 5) * 4;
    const int bb  = bk >> 3;
    const int bp  = (bk & 7) >> 1;

    floatx4 acc[4][4];
    #pragma unroll
    for (int i = 0; i < 4; i++)
        #pragma unroll
        for (int j = 0; j < 4; j++)
            #pragma unroll
            for (int e = 0; e < 4; e++) acc[i][j][e] = 0.0f;

    for (int k0 = 0; k0 < K; k0 += 32) {
        if (k0) __syncthreads();
        // ---- stage A ----
        if (AMODE == 0) {
            float f[16];
            #pragma unroll
            for (int i = 0; i < 4; i++)
                *(float4*)&f[i * 4] =
                    *(const float4*)&Af[(size_t)(m0 + ar) * K + k0 + ab0 * 8 + i * 4];
            uint32_t hi[8], lo[8];
            #pragma unroll
            for (int j = 0; j < 8; j++) split2(f[2 * j], f[2 * j + 1], hi[j], lo[j]);
            int i0 = ar * 16 + ((ab0 ^ as) * 4);
            int i1 = ar * 16 + (((ab0 + 1) ^ as) * 4);
            *(uint4*)&Ah[i0] = make_uint4(hi[0], hi[1], hi[2], hi[3]);
            *(uint4*)&Ah[i1] = make_uint4(hi[4], hi[5], hi[6], hi[7]);
            *(uint4*)&Al[i0] = make_uint4(lo[0], lo[1], lo[2], lo[3]);
            *(uint4*)&Al[i1] = make_uint4(lo[4], lo[5], lo[6], lo[7]);
        } else {
            #pragma unroll
            for (int i = 0; i < 2; i++) {
                int idx = t + i * 256;
                int row = idx >> 2, kb = idx & 3;
                size_t src = (size_t)(m0 + row) * Kw + (k0 >> 1) + kb * 4;
                int dst = row * 16 + ((kb ^ swz(row)) * 4);
                *(uint4*)&Ah[dst] = *(const uint4*)&Ahg[src];
                *(uint4*)&Al[dst] = *(const uint4*)&Alg[src];
            }
        }
        // ---- stage B ----
        if (BMODE == 0) {
            float4 g[4];
            #pragma unroll
            for (int j = 0; j < 4; j++)
                g[j] = *(const float4*)&Bf[(size_t)(k0 + bk + j) * N + n0 + bc];
            #pragma unroll
            for (int nn = 0; nn < 4; nn++) {
                int n = bc + nn;
                float e0 = ((const float*)&g[0])[nn];
                float e1 = ((const float*)&g[1])[nn];
                float e2 = ((const float*)&g[2])[nn];
                float e3 = ((const float*)&g[3])[nn];
                uint32_t h0, q0, h1, q1;
                split2(e0, e1, h0, q0);
                split2(e2, e3, h1, q1);
                int bi = n * 16 + ((bb ^ swz(n)) * 4) + bp;
                *(uint2*)&Bh[bi] = make_uint2(h0, h1);
                *(uint2*)&Bl[bi] = make_uint2(q0, q1);
            }
        } else {
            #pragma unroll
            for (int i = 0; i < 2; i++) {
                int idx = t + i * 256;
                int row = idx >> 2, kb = idx & 3;
                size_t src = (size_t)(n0 + row) * Kw + (k0 >> 1) + kb * 4;
                int dst = row * 16 + ((kb ^ swz(row)) * 4);
                *(uint4*)&Bh[dst] = *(const uint4*)&Bth[src];
                *(uint4*)&Bl[dst] = *(const uint4*)&Btl[src];
            }
        }
        __syncthreads();

        // ---- fragments + swapped MFMA: D = C^T, lane l15 = C-row ----
        bf16x8 vbh[4], vbl[4];
        #pragma unroll
        for (int fn = 0; fn < 4; fn++) {
            int br = wn * 64 + fn * 16 + l15;
            int bi = br * 16 + ((quad ^ swz(br)) * 4);
            vbh[fn] = *(const bf16x8*)&Bh[bi];
            vbl[fn] = *(const bf16x8*)&Bl[bi];
        }
        #pragma unroll
        for (int fm = 0; fm < 4; fm++) {
            int arow = wm * 64 + fm * 16 + l15;
            int ai = arow * 16 + ((quad ^ swz(arow)) * 4);
            bf16x8 vah = *(const bf16x8*)&Ah[ai];
            bf16x8 val = *(const bf16x8*)&Al[ai];
            #pragma unroll
            for (int fn = 0; fn < 4; fn++) {
                acc[fm][fn] = __builtin_amdgcn_mfma_f32_16x16x32_bf16(vbh[fn], vah, acc[fm][fn], 0, 0, 0);
                acc[fm][fn] = __builtin_amdgcn_mfma_f32_16x16x32_bf16(vbl[fn], vah, acc[fm][fn], 0, 0, 0);
                acc[fm][fn] = __builtin_amdgcn_mfma_f32_16x16x32_bf16(vbh[fn], val, acc[fm][fn], 0, 0, 0);
            }
        }
    }

    // ---- epilogue: C-row = m0+wm*64+fm*16+l15 ; C-cols = colb..colb+3 ----
    #pragma unroll
    for (int fm = 0; fm < 4; fm++) {
        int row = m0 + wm * 64 + fm * 16 + l15;
        #pragma unroll
        for (int fn = 0; fn < 4; fn++) {
            int colb = n0 + wn * 64 + fn * 16 + quad * 4;
            floatx4 a = acc[fm][fn];
            if (EPI == 0) {
                float4 bb4 = *(const float4*)&bias[colb];
                float4 v;
                v.x = a[0] + bb4.x; v.y = a[1] + bb4.y;
                v.z = a[2] + bb4.z; v.w = a[3] + bb4.w;
                *(float4*)&Cf[(size_t)row * N + colb] = v;
            } else if (EPI == 1) {
                if (colb < 1024) {
                    uint32_t h0, l0, h1, l1;
                    split2(a[0], a[1], h0, l0);
                    split2(a[2], a[3], h1, l1);
                    size_t wi = (size_t)row * 512 + (colb >> 1);
                    *(uint2*)&O1h[wi] = make_uint2(h0, h1);
                    *(uint2*)&O1l[wi] = make_uint2(l0, l1);
                } else {
                    uint32_t w0 = pack_bf16_rne(a[0], a[1]);
                    uint32_t w1 = pack_bf16_rne(a[2], a[3]);
                    *(uint2*)&O2[(size_t)row * 512 + ((colb - 1024) >> 1)] = make_uint2(w0, w1);
                }
            } else {
                uint32_t h0, l0, h1, l1;
                split2(a[0], a[1], h0, l0);
                split2(a[2], a[3], h1, l1);
                size_t wi = (size_t)row * 512 + (colb >> 1);
                *(uint2*)&O1h[wi] = make_uint2(h0, h1);
                *(uint2*)&O1l[wi] = make_uint2(l0, l1);
            }
        }
    }
}

// ---------------- MFMA flash attention, pre-split bf16 inputs ---------------
// Qh/Ql/Kh/Kl: [B*N][512 words] split bf16; Vb same, plain bf16.
// Output: xh/xl split bf16 [B*N][512 words]. Structure identical to R3.
#define FSTR 36
__global__ __launch_bounds__(256, 2)
void flash_attn(const uint32_t* __restrict__ qhg, const uint32_t* __restrict__ qlg,
                const uint32_t* __restrict__ khg, const uint32_t* __restrict__ klg,
                const uint32_t* __restrict__ vbg,
                uint32_t* __restrict__ xhg, uint32_t* __restrict__ xlg)
{
    __shared__ uint32_t Qh[64 * FSTR], Ql[64 * FSTR];
    __shared__ uint32_t Kh[64 * FSTR], Kl[64 * FSTR];
    __shared__ uint32_t Vt[64 * FSTR];
    __shared__ uint32_t Pt[64 * FSTR];

    const int t    = threadIdx.x;
    const int lane = t & 63;
    const int w    = t >> 6;
    const int quad = lane >> 4, l15 = lane & 15;
    const int qb = blockIdx.x;
    const int h  = blockIdx.y;
    const int b  = blockIdx.z;
    const float scale = 0.125f;

    const size_t rowbase = (size_t)b * SEQ;
    const int qrow = w * 16 + l15;

    // ---- stage Q tile once: pure copies ----
    #pragma unroll
    for (int i = 0; i < 2; i++) {
        int idx = t + i * 256;
        int row = idx >> 3, w4 = (idx & 7) * 4;
        size_t gw = (rowbase + qb * 64 + row) * 512 + h * 32 + w4;
        *(uint4*)&Qh[row * FSTR + w4] = *(const uint4*)&qhg[gw];
        *(uint4*)&Ql[row * FSTR + w4] = *(const uint4*)&qlg[gw];
    }

    float m_i = -INFINITY, l_i = 0.0f;
    floatx4 acc_o[4];
    #pragma unroll
    for (int fm = 0; fm < 4; fm++)
        #pragma unroll
        for (int e = 0; e < 4; e++) acc_o[fm][e] = 0.0f;

    for (int kt = 0; kt < SEQ / 64; kt++) {
        __syncthreads();
        // ---- stage K tile: pure copies ----
        #pragma unroll
        for (int i = 0; i < 2; i++) {
            int idx = t + i * 256;
            int row = idx >> 3, w4 = (idx & 7) * 4;
            size_t gw = (rowbase + kt * 64 + row) * 512 + h * 32 + w4;
            *(uint4*)&Kh[row * FSTR + w4] = *(const uint4*)&khg[gw];
            *(uint4*)&Kl[row * FSTR + w4] = *(const uint4*)&klg[gw];
        }
        // ---- stage V transposed from bf16 ----
        {
            int key0 = (t & 15) * 4, d0 = (t >> 4) * 4;
            uint2 v0 = *(const uint2*)&vbg[(rowbase + kt * 64 + key0 + 0) * 512 + h * 32 + (d0 >> 1)];
            uint2 v1 = *(const uint2*)&vbg[(rowbase + kt * 64 + key0 + 1) * 512 + h * 32 + (d0 >> 1)];
            uint2 v2 = *(const uint2*)&vbg[(rowbase + kt * 64 + key0 + 2) * 512 + h * 32 + (d0 >> 1)];
            uint2 v3 = *(const uint2*)&vbg[(rowbase + kt * 64 + key0 + 3) * 512 + h * 32 + (d0 >> 1)];
            uint32_t lo, hi;
            // j=0: d0, from .x low halves
            lo = (v0.x & 0xFFFFu) | (v1.x << 16);
            hi = (v2.x & 0xFFFFu) | (v3.x << 16);
            *(uint2*)&Vt[(d0 + 0) * FSTR + (key0 >> 1)] = make_uint2(lo, hi);
            // j=1: d0+1, from .x high halves
            lo = (v0.x >> 16) | (v1.x & 0xFFFF0000u);
            hi = (v2.x >> 16) | (v3.x & 0xFFFF0000u);
            *(uint2*)&Vt[(d0 + 1) * FSTR + (key0 >> 1)] = make_uint2(lo, hi);
            // j=2: d0+2, from .y low halves
            lo = (v0.y & 0xFFFFu) | (v1.y << 16);
            hi = (v2.y & 0xFFFFu) | (v3.y << 16);
            *(uint2*)&Vt[(d0 + 2) * FSTR + (key0 >> 1)] = make_uint2(lo, hi);
            // j=3: d0+3, from .y high halves
            lo = (v0.y >> 16) | (v1.y & 0xFFFF0000u);
            hi = (v2.y >> 16) | (v3.y & 0xFFFF0000u);
            *(uint2*)&Vt[(d0 + 3) * FSTR + (key0 >> 1)] = make_uint2(lo, hi);
        }
        __syncthreads();

        // ---- S^T = K·Q^T (bf16x3) ----
        floatx4 sacc[4];
        #pragma unroll
        for (int fm = 0; fm < 4; fm++)
            #pragma unroll
            for (int e = 0; e < 4; e++) sacc[fm][e] = 0.0f;

        #pragma unroll
        for (int s = 0; s < 2; s++) {
            int qi = qrow * FSTR + s * 16 + quad * 4;
            bf16x8 vqh = *(const bf16x8*)&Qh[qi];
            bf16x8 vql = *(const bf16x8*)&Ql[qi];
            #pragma unroll
            for (int fm = 0; fm < 4; fm++) {
                int ki = (fm * 16 + l15) * FSTR + s * 16 + quad * 4;
                bf16x8 vkh = *(const bf16x8*)&Kh[ki];
                bf16x8 vkl = *(const bf16x8*)&Kl[ki];
                sacc[fm] = __builtin_amdgcn_mfma_f32_16x16x32_bf16(vkh, vqh, sacc[fm], 0, 0, 0);
                sacc[fm] = __builtin_amdgcn_mfma_f32_16x16x32_bf16(vkh, vql, sacc[fm], 0, 0, 0);
                sacc[fm] = __builtin_amdgcn_mfma_f32_16x16x32_bf16(vkl, vqh, sacc[fm], 0, 0, 0);
            }
        }

        // ---- online softmax (scalar per lane) ----
        float p[4][4];
        float mt = -INFINITY;
        #pragma unroll
        for (int fm = 0; fm < 4; fm++)
            #pragma unroll
            for (int r = 0; r < 4; r++) {
                p[fm][r] = sacc[fm][r] * scale;
                mt = fmaxf(mt, p[fm][r]);
            }
        mt = fmaxf(mt, __shfl_xor(mt, 16));
        mt = fmaxf(mt, __shfl_xor(mt, 32));
        float m_new = fmaxf(m_i, mt);
        float alpha = __expf(m_i - m_new);
        float rs = 0.0f;
        #pragma unroll
        for (int fm = 0; fm < 4; fm++)
            #pragma unroll
            for (int r = 0; r < 4; r++) {
                p[fm][r] = __expf(p[fm][r] - m_new);
                rs += p[fm][r];
            }
        rs += __shfl_xor(rs, 16);
        rs += __shfl_xor(rs, 32);
        l_i = l_i * alpha + rs;
        m_i = m_new;
        #pragma unroll
        for (int fm = 0; fm < 4; fm++)
            #pragma unroll
            for (int e = 0; e < 4; e++) acc_o[fm][e] *= alpha;

        // ---- P -> LDS [qrow][key] (wave-private rows, no barrier) ----
        #pragma unroll
        for (int fm = 0; fm < 4; fm++) {
            uint32_t u0 = pack_bf16_rne(p[fm][0], p[fm][1]);
            uint32_t u1 = pack_bf16_rne(p[fm][2], p[fm][3]);
            *(uint2*)&Pt[qrow * FSTR + fm * 8 + quad * 2] = make_uint2(u0, u1);
        }

        // ---- O^T += Vt · P^T ----
        #pragma unroll
        for (int s = 0; s < 2; s++) {
            bf16x8 pb = *(const bf16x8*)&Pt[qrow * FSTR + s * 16 + quad * 4];
            #pragma unroll
            for (int fm = 0; fm < 4; fm++) {
                bf16x8 va = *(const bf16x8*)&Vt[(fm * 16 + l15) * FSTR + s * 16 + quad * 4];
                acc_o[fm] = __builtin_amdgcn_mfma_f32_16x16x32_bf16(va, pb, acc_o[fm], 0, 0, 0);
            }
        }
    }

    // ---- epilogue: write x pre-split bf16 ----
    float rl = 1.0f / l_i;
    size_t row = rowbase + qb * 64 + qrow;
    #pragma unroll
    for (int fm = 0; fm < 4; fm++) {
        int d0 = fm * 16 + quad * 4;
        uint32_t h0, l0, h1, l1;
        split2(acc_o[fm][0] * rl, acc_o[fm][1] * rl, h0, l0);
        split2(acc_o[fm][2] * rl, acc_o[fm][3] * rl, h1, l1);
        size_t wi = row * 512 + ((h * 64 + d0) >> 1);
        *(uint2*)&xhg[wi] = make_uint2(h0, h1);
        *(uint2*)&xlg[wi] = make_uint2(l0, l1);
    }
}

extern "C" void kernel_launch(void* const* d_in, const int* in_sizes, int n_in,
                              void* d_out, int out_size, void* d_ws, size_t ws_size,
                              hipStream_t stream)
{
    const float* input_qv = (const float*)d_in[0];
    const float* input_k  = (const float*)d_in[1];
    const float* W_qv     = (const float*)d_in[2];
    const float* W_k      = (const float*)d_in[3];
    const float* W_proj   = (const float*)d_in[4];
    const float* b_proj   = (const float*)d_in[5];
    float* out = (float*)d_out;

    const int M = BATCH * SEQ;                       // 4096
    const size_t RW = 4096 * 512;                    // words per [M][1024-bf16] buffer

    uint32_t* qh = (uint32_t*)d_ws;                  // 5 x 8.4 MB = 41.9 MB
    uint32_t* ql = qh + RW;
    uint32_t* vb = ql + RW;
    uint32_t* xh = vb + RW;
    uint32_t* xl = xh + RW;
    uint32_t* kh = (uint32_t*)d_out;                 // park split K in d_out (16.8 MB
    uint32_t* kl = kh + RW;                          // exactly); proj rewrites out after

    // pre-split transposed weights if workspace allows (58.7 MB total)
    const size_t wneed = (5 * RW + 2 * (2048 * 512) + 4 * (1024 * 512)) * 4;
    dim3 blk(256);

    if (ws_size >= wneed) {
        uint32_t* w1h = xl + RW;
        uint32_t* w1l = w1h + 2048 * 512;
        uint32_t* w2h = w1l + 2048 * 512;
        uint32_t* w2l = w2h + 1024 * 512;
        uint32_t* w3h = w2l + 1024 * 512;
        uint32_t* w3l = w3h + 1024 * 512;
        convert_w<<<dim3(64, 16), blk, 0, stream>>>(W_qv, W_k, W_proj,
                                                    w1h, w1l, w2h, w2l, w3h, w3l);
        gemm_k<0, 1, 1><<<dim3(16, 32), blk, 0, stream>>>(
            input_qv, nullptr, nullptr, nullptr, w1h, w1l,
            nullptr, nullptr, qh, ql, vb, M, 2048, 1024);
        gemm_k<0, 1, 2><<<dim3(8, 32), blk, 0, stream>>>(
            input_k, nullptr, nullptr, nullptr, w2h, w2l,
            nullptr, nullptr, kh, kl, nullptr, M, 1024, 1024);
        flash_attn<<<dim3(SEQ / 64, NH, BATCH), blk, 0, stream>>>(
            qh, ql, kh, kl, vb, xh, xl);
        gemm_k<1, 1, 0><<<dim3(8, 32), blk, 0, stream>>>(
            nullptr, xh, xl, nullptr, w3h, w3l,
            b_proj, out, nullptr, nullptr, nullptr, M, 1024, 1024);
    } else {
        gemm_k<0, 0, 1><<<dim3(16, 32), blk, 0, stream>>>(
            input_qv, nullptr, nullptr, W_qv, nullptr, nullptr,
            nullptr, nullptr, qh, ql, vb, M, 2048, 1024);
        gemm_k<0, 0, 2><<<dim3(8, 32), blk, 0, stream>>>(
            input_k, nullptr, nullptr, W_k, nullptr, nullptr,
            nullptr, nullptr, kh, kl, nullptr, M, 1024, 1024);
        flash_attn<<<dim3(SEQ / 64, NH, BATCH), blk, 0, stream>>>(
            qh, ql, kh, kl, vb, xh, xl);
        gemm_k<1, 0, 0><<<dim3(8, 32), blk, 0, stream>>>(
            nullptr, xh, xl, W_proj, nullptr, nullptr,
            b_proj, out, nullptr, nullptr, nullptr, M, 1024, 1024);
    }
}

// Round 5
// 373.499 us; speedup vs baseline: 2.8700x; 1.1019x over previous
//
#include <hip/hip_runtime.h>
#include <stdint.h>

#define BATCH 2
#define SEQ   2048
#define DIM   1024
#define NH    16
#define DH    64

typedef short bf16x8 __attribute__((ext_vector_type(8)));
typedef float floatx4 __attribute__((ext_vector_type(4)));

// Split two fp32 into packed bf16 hi-pair and lo-pair (truncation split)
__device__ __forceinline__ void split2(float x0, float x1, uint32_t& hi, uint32_t& lo) {
    uint32_t u0 = __float_as_uint(x0), u1 = __float_as_uint(x1);
    uint32_t m0 = u0 & 0xFFFF0000u;
    uint32_t m1 = u1 & 0xFFFF0000u;
    hi = (u0 >> 16) | m1;
    float l0 = x0 - __uint_as_float(m0);
    float l1 = x1 - __uint_as_float(m1);
    lo = (__float_as_uint(l0) >> 16) | (__float_as_uint(l1) & 0xFFFF0000u);
}

__device__ __forceinline__ uint32_t pack_bf16_rne(float x0, float x1) {
    uint32_t u0 = __float_as_uint(x0), u1 = __float_as_uint(x1);
    u0 += 0x7FFFu + ((u0 >> 16) & 1);
    u1 += 0x7FFFu + ((u1 >> 16) & 1);
    return (u0 >> 16) | (u1 & 0xFFFF0000u);
}

// async global->LDS, 16 B per lane. LDS dest must equal wave-uniform base + lane*16.
__device__ __forceinline__ void dma16(uint32_t* lds, const uint32_t* g) {
    __builtin_amdgcn_global_load_lds(
        (const __attribute__((address_space(1))) uint32_t*)g,
        (__attribute__((address_space(3))) uint32_t*)lds, 16, 0, 0);
}

// ---------------- one-time weight convert: fp32 [K][N] -> bf16 h/l [N][K] ---
__global__ __launch_bounds__(256)
void convert_w(const float* __restrict__ Wqv, const float* __restrict__ Wk,
               const float* __restrict__ Wp,
               uint32_t* __restrict__ w1h, uint32_t* __restrict__ w1l,
               uint32_t* __restrict__ w2h, uint32_t* __restrict__ w2l,
               uint32_t* __restrict__ w3h, uint32_t* __restrict__ w3l)
{
    __shared__ ushort Lh[64][68], Ll[64][68];
    const int bx = blockIdx.x;
    const int k0 = blockIdx.y * 64;
    const float* src; uint32_t *dh, *dl; int N, n0;
    if (bx < 32)      { src = Wqv; dh = w1h; dl = w1l; N = 2048; n0 = bx * 64; }
    else if (bx < 48) { src = Wk;  dh = w2h; dl = w2l; N = 1024; n0 = (bx - 32) * 64; }
    else              { src = Wp;  dh = w3h; dl = w3l; N = 1024; n0 = (bx - 48) * 64; }
    const int t = threadIdx.x;
    const int n4 = (t & 15) * 4, kr = t >> 4;
    #pragma unroll
    for (int it = 0; it < 4; it++) {
        int k = kr + it * 16;
        float4 f = *(const float4*)&src[(size_t)(k0 + k) * N + n0 + n4];
        float ff[4] = {f.x, f.y, f.z, f.w};
        #pragma unroll
        for (int j = 0; j < 4; j++) {
            uint32_t u = __float_as_uint(ff[j]);
            uint32_t m = u & 0xFFFF0000u;
            Lh[k][n4 + j] = (ushort)(u >> 16);
            float lo = ff[j] - __uint_as_float(m);
            Ll[k][n4 + j] = (ushort)(__float_as_uint(lo) >> 16);
        }
    }
    __syncthreads();
    const int n = t >> 2, wk = (t & 3) * 8;
    uint32_t oh[8], ol[8];
    #pragma unroll
    for (int w = 0; w < 8; w++) {
        int kk = 2 * (wk + w);
        oh[w] = (uint32_t)Lh[kk][n] | ((uint32_t)Lh[kk + 1][n] << 16);
        ol[w] = (uint32_t)Ll[kk][n] | ((uint32_t)Ll[kk + 1][n] << 16);
    }
    size_t dst = (size_t)(n0 + n) * 512 + (k0 >> 1) + wk;
    *(uint4*)&dh[dst]     = make_uint4(oh[0], oh[1], oh[2], oh[3]);
    *(uint4*)&dh[dst + 4] = make_uint4(oh[4], oh[5], oh[6], oh[7]);
    *(uint4*)&dl[dst]     = make_uint4(ol[0], ol[1], ol[2], ol[3]);
    *(uint4*)&dl[dst + 4] = make_uint4(ol[4], ol[5], ol[6], ol[7]);
}

// ---------------- input convert: fp32 [4096][1024] -> split h/l words -------
// 4096 blocks: bx<2048 -> input_qv, else input_k.
__global__ __launch_bounds__(256)
void convert_in(const float* __restrict__ qv_in, const float* __restrict__ k_in,
                uint32_t* __restrict__ aqh, uint32_t* __restrict__ aql,
                uint32_t* __restrict__ akh, uint32_t* __restrict__ akl)
{
    int bid = blockIdx.x;
    const float* src; uint32_t *dh, *dl;
    if (bid < 2048) { src = qv_in; dh = aqh; dl = aql; }
    else            { src = k_in;  dh = akh; dl = akl; bid -= 2048; }
    size_t fbase = (size_t)bid * 2048 + threadIdx.x * 8;
    float f[8];
    *(float4*)&f[0] = *(const float4*)&src[fbase];
    *(float4*)&f[4] = *(const float4*)&src[fbase + 4];
    uint32_t h[4], l[4];
    #pragma unroll
    for (int j = 0; j < 4; j++) split2(f[2 * j], f[2 * j + 1], h[j], l[j]);
    size_t wbase = fbase >> 1;
    *(uint4*)&dh[wbase] = make_uint4(h[0], h[1], h[2], h[3]);
    *(uint4*)&dl[wbase] = make_uint4(l[0], l[1], l[2], l[3]);
}

// ---------------- bf16x3 MFMA GEMM, global_load_lds staging -----------------
// AMODE 1: pre-split A [M][K/2] words, DMA. AMODE 0: fp32 A, in-kernel split.
// BMODE 1: pre-split B^T [N][K/2] words, DMA. BMODE 0: fp32 B [K][N], split+transpose.
// EPI: 0 = fp32+bias -> Cf; 1 = qv (cols<1024 split -> O1h/O1l, else bf16 -> O2);
//      2 = split -> O1h/O1l
template<int AMODE, int BMODE, int EPI>
__global__ __launch_bounds__(256, 3)
void gemm_lds(const float* __restrict__ Af,
              const uint32_t* __restrict__ Ahg, const uint32_t* __restrict__ Alg,
              const float* __restrict__ Bf,
              const uint32_t* __restrict__ Bth, const uint32_t* __restrict__ Btl,
              const float* __restrict__ bias, float* __restrict__ Cf,
              uint32_t* __restrict__ O1h, uint32_t* __restrict__ O1l,
              uint32_t* __restrict__ O2,
              int M, int N, int K)
{
    __shared__ uint32_t Ah[128 * 16], Al[128 * 16], Bh[128 * 16], Bl[128 * 16];

    const int t    = threadIdx.x;
    const int lane = t & 63;
    const int w    = t >> 6;
    const int wm   = w & 1, wn = w >> 1;
    const int quad = lane >> 4, l15 = lane & 15;
    const int m0 = blockIdx.y * 128, n0 = blockIdx.x * 128;
    const int Kw = K >> 1;

    // DMA coords: instr i in {0,1}: LDS u32 base (i*4+w)*256, lane covers +lane*4..+3
    const int drow = w * 16 + (lane >> 2);   // + i*64
    const int dcol = (lane & 3) * 4;
    // fp32-A staging coords
    const int ar  = t >> 1;
    const int ab0 = (t & 1) * 2;
    // fp32-B staging coords
    const int bc  = (t & 31) * 4;
    const int bk  = (t >> 5) * 4;
    const int bb  = bk >> 3;
    const int bp  = (bk & 7) >> 1;

    floatx4 acc[4][4];
    #pragma unroll
    for (int i = 0; i < 4; i++)
        #pragma unroll
        for (int j = 0; j < 4; j++)
            #pragma unroll
            for (int e = 0; e < 4; e++) acc[i][j][e] = 0.0f;

    for (int k0 = 0; k0 < K; k0 += 32) {
        if (k0) __syncthreads();
        // ---- stage A ----
        if (AMODE == 1) {
            #pragma unroll
            for (int i = 0; i < 2; i++) {
                int row = i * 64 + drow;
                size_t g = (size_t)(m0 + row) * Kw + (k0 >> 1) + dcol;
                int d = (i * 4 + w) * 256 + lane * 4;
                dma16(&Ah[d], &Ahg[g]);
                dma16(&Al[d], &Alg[g]);
            }
        } else {
            float f[16];
            #pragma unroll
            for (int i = 0; i < 4; i++)
                *(float4*)&f[i * 4] =
                    *(const float4*)&Af[(size_t)(m0 + ar) * K + k0 + ab0 * 8 + i * 4];
            uint32_t hi[8], lo[8];
            #pragma unroll
            for (int j = 0; j < 8; j++) split2(f[2 * j], f[2 * j + 1], hi[j], lo[j]);
            int i0 = ar * 16 + ab0 * 4;
            *(uint4*)&Ah[i0]     = make_uint4(hi[0], hi[1], hi[2], hi[3]);
            *(uint4*)&Ah[i0 + 4] = make_uint4(hi[4], hi[5], hi[6], hi[7]);
            *(uint4*)&Al[i0]     = make_uint4(lo[0], lo[1], lo[2], lo[3]);
            *(uint4*)&Al[i0 + 4] = make_uint4(lo[4], lo[5], lo[6], lo[7]);
        }
        // ---- stage B ----
        if (BMODE == 1) {
            #pragma unroll
            for (int i = 0; i < 2; i++) {
                int row = i * 64 + drow;
                size_t g = (size_t)(n0 + row) * Kw + (k0 >> 1) + dcol;
                int d = (i * 4 + w) * 256 + lane * 4;
                dma16(&Bh[d], &Bth[g]);
                dma16(&Bl[d], &Btl[g]);
            }
        } else {
            float4 g4[4];
            #pragma unroll
            for (int j = 0; j < 4; j++)
                g4[j] = *(const float4*)&Bf[(size_t)(k0 + bk + j) * N + n0 + bc];
            #pragma unroll
            for (int nn = 0; nn < 4; nn++) {
                int n = bc + nn;
                float e0 = ((const float*)&g4[0])[nn];
                float e1 = ((const float*)&g4[1])[nn];
                float e2 = ((const float*)&g4[2])[nn];
                float e3 = ((const float*)&g4[3])[nn];
                uint32_t h0, q0, h1, q1;
                split2(e0, e1, h0, q0);
                split2(e2, e3, h1, q1);
                int bi = n * 16 + bb * 4 + bp;
                *(uint2*)&Bh[bi] = make_uint2(h0, h1);
                *(uint2*)&Bl[bi] = make_uint2(q0, q1);
            }
        }
        __syncthreads();

        // ---- fragments + swapped MFMA: lane l15 = C-row ----
        bf16x8 vbh[4], vbl[4];
        #pragma unroll
        for (int fn = 0; fn < 4; fn++) {
            int bi = (wn * 64 + fn * 16 + l15) * 16 + quad * 4;
            vbh[fn] = *(const bf16x8*)&Bh[bi];
            vbl[fn] = *(const bf16x8*)&Bl[bi];
        }
        #pragma unroll
        for (int fm = 0; fm < 4; fm++) {
            int ai = (wm * 64 + fm * 16 + l15) * 16 + quad * 4;
            bf16x8 vah = *(const bf16x8*)&Ah[ai];
            bf16x8 val = *(const bf16x8*)&Al[ai];
            #pragma unroll
            for (int fn = 0; fn < 4; fn++) {
                acc[fm][fn] = __builtin_amdgcn_mfma_f32_16x16x32_bf16(vbh[fn], vah, acc[fm][fn], 0, 0, 0);
                acc[fm][fn] = __builtin_amdgcn_mfma_f32_16x16x32_bf16(vbl[fn], vah, acc[fm][fn], 0, 0, 0);
                acc[fm][fn] = __builtin_amdgcn_mfma_f32_16x16x32_bf16(vbh[fn], val, acc[fm][fn], 0, 0, 0);
            }
        }
    }

    // ---- epilogue ----
    #pragma unroll
    for (int fm = 0; fm < 4; fm++) {
        int row = m0 + wm * 64 + fm * 16 + l15;
        #pragma unroll
        for (int fn = 0; fn < 4; fn++) {
            int colb = n0 + wn * 64 + fn * 16 + quad * 4;
            floatx4 a = acc[fm][fn];
            if (EPI == 0) {
                float4 bb4 = *(const float4*)&bias[colb];
                float4 v;
                v.x = a[0] + bb4.x; v.y = a[1] + bb4.y;
                v.z = a[2] + bb4.z; v.w = a[3] + bb4.w;
                *(float4*)&Cf[(size_t)row * N + colb] = v;
            } else if (EPI == 1) {
                if (colb < 1024) {
                    uint32_t h0, l0, h1, l1;
                    split2(a[0], a[1], h0, l0);
                    split2(a[2], a[3], h1, l1);
                    size_t wi = (size_t)row * 512 + (colb >> 1);
                    *(uint2*)&O1h[wi] = make_uint2(h0, h1);
                    *(uint2*)&O1l[wi] = make_uint2(l0, l1);
                } else {
                    uint32_t w0 = pack_bf16_rne(a[0], a[1]);
                    uint32_t w1 = pack_bf16_rne(a[2], a[3]);
                    *(uint2*)&O2[(size_t)row * 512 + ((colb - 1024) >> 1)] = make_uint2(w0, w1);
                }
            } else {
                uint32_t h0, l0, h1, l1;
                split2(a[0], a[1], h0, l0);
                split2(a[2], a[3], h1, l1);
                size_t wi = (size_t)row * 512 + (colb >> 1);
                *(uint2*)&O1h[wi] = make_uint2(h0, h1);
                *(uint2*)&O1l[wi] = make_uint2(l0, l1);
            }
        }
    }
}

// ---------------- MFMA flash attention, Br=128, Bc=64 -----------------------
// 4 waves; wave w owns Q rows w*32 .. w*32+31 (2 n-frags of 16).
// S^T = K·Q^T (bf16x3) -> lane holds 2 qrows (one per n-frag); online softmax
// scalar per (lane, nf); P -> LDS [qrow][key] wave-private; O^T = Vt·P^T.
// All LDS rows stride 34 u32 (136 B): frag reads = 2 lanes/bank (free, m136).
#define FST 34
__global__ __launch_bounds__(256, 2)
void flash_attn(const uint32_t* __restrict__ qhg, const uint32_t* __restrict__ qlg,
                const uint32_t* __restrict__ khg, const uint32_t* __restrict__ klg,
                const uint32_t* __restrict__ vbg,
                uint32_t* __restrict__ xhg, uint32_t* __restrict__ xlg)
{
    __shared__ uint32_t Qh[128 * FST], Ql[128 * FST];
    __shared__ uint32_t Kh[64 * FST],  Kl[64 * FST];
    __shared__ uint32_t Vt[64 * FST];
    __shared__ uint32_t Pt[128 * FST];

    const int t    = threadIdx.x;
    const int lane = t & 63;
    const int w    = t >> 6;
    const int quad = lane >> 4, l15 = lane & 15;
    const int qb = blockIdx.x;
    const int h  = blockIdx.y;
    const int b  = blockIdx.z;
    const float scale = 0.125f;

    const size_t rowbase = (size_t)b * SEQ;

    // ---- stage Q tile once: 128 rows x 32 words, h+l ----
    {
        int row = t >> 1, c0 = (t & 1) * 16;
        size_t gw = (rowbase + qb * 128 + row) * 512 + h * 32 + c0;
        #pragma unroll
        for (int j = 0; j < 4; j++) {
            *(uint4*)&Qh[row * FST + c0 + j * 4] = *(const uint4*)&qhg[gw + j * 4];
            *(uint4*)&Ql[row * FST + c0 + j * 4] = *(const uint4*)&qlg[gw + j * 4];
        }
    }

    float m_i[2] = {-INFINITY, -INFINITY};
    float l_i[2] = {0.0f, 0.0f};
    floatx4 acc_o[2][4];
    #pragma unroll
    for (int nf = 0; nf < 2; nf++)
        #pragma unroll
        for (int fm = 0; fm < 4; fm++)
            #pragma unroll
            for (int e = 0; e < 4; e++) acc_o[nf][fm][e] = 0.0f;

    for (int kt = 0; kt < SEQ / 64; kt++) {
        __syncthreads();
        // ---- stage K tile: 64 rows x 32 words, h+l ----
        {
            int row = t >> 2, c0 = (t & 3) * 8;
            size_t gw = (rowbase + kt * 64 + row) * 512 + h * 32 + c0;
            *(uint4*)&Kh[row * FST + c0]     = *(const uint4*)&khg[gw];
            *(uint4*)&Kh[row * FST + c0 + 4] = *(const uint4*)&khg[gw + 4];
            *(uint4*)&Kl[row * FST + c0]     = *(const uint4*)&klg[gw];
            *(uint4*)&Kl[row * FST + c0 + 4] = *(const uint4*)&klg[gw + 4];
        }
        // ---- stage V transposed: Vt[d][key] ----
        {
            int key0 = (t & 15) * 4, d0 = (t >> 4) * 4;
            uint2 v0 = *(const uint2*)&vbg[(rowbase + kt * 64 + key0 + 0) * 512 + h * 32 + (d0 >> 1)];
            uint2 v1 = *(const uint2*)&vbg[(rowbase + kt * 64 + key0 + 1) * 512 + h * 32 + (d0 >> 1)];
            uint2 v2 = *(const uint2*)&vbg[(rowbase + kt * 64 + key0 + 2) * 512 + h * 32 + (d0 >> 1)];
            uint2 v3 = *(const uint2*)&vbg[(rowbase + kt * 64 + key0 + 3) * 512 + h * 32 + (d0 >> 1)];
            uint32_t lo, hi;
            lo = (v0.x & 0xFFFFu) | (v1.x << 16);
            hi = (v2.x & 0xFFFFu) | (v3.x << 16);
            *(uint2*)&Vt[(d0 + 0) * FST + (key0 >> 1)] = make_uint2(lo, hi);
            lo = (v0.x >> 16) | (v1.x & 0xFFFF0000u);
            hi = (v2.x >> 16) | (v3.x & 0xFFFF0000u);
            *(uint2*)&Vt[(d0 + 1) * FST + (key0 >> 1)] = make_uint2(lo, hi);
            lo = (v0.y & 0xFFFFu) | (v1.y << 16);
            hi = (v2.y & 0xFFFFu) | (v3.y << 16);
            *(uint2*)&Vt[(d0 + 2) * FST + (key0 >> 1)] = make_uint2(lo, hi);
            lo = (v0.y >> 16) | (v1.y & 0xFFFF0000u);
            hi = (v2.y >> 16) | (v3.y & 0xFFFF0000u);
            *(uint2*)&Vt[(d0 + 3) * FST + (key0 >> 1)] = make_uint2(lo, hi);
        }
        __syncthreads();

        // ---- S^T = K·Q^T (bf16x3), 2 n-frags per wave ----
        floatx4 sacc[2][4];
        #pragma unroll
        for (int nf = 0; nf < 2; nf++)
            #pragma unroll
            for (int fm = 0; fm < 4; fm++)
                #pragma unroll
                for (int e = 0; e < 4; e++) sacc[nf][fm][e] = 0.0f;

        #pragma unroll
        for (int s = 0; s < 2; s++) {
            bf16x8 vqh[2], vql[2];
            #pragma unroll
            for (int nf = 0; nf < 2; nf++) {
                int qi = (w * 32 + nf * 16 + l15) * FST + s * 16 + quad * 4;
                vqh[nf] = *(const bf16x8*)&Qh[qi];
                vql[nf] = *(const bf16x8*)&Ql[qi];
            }
            #pragma unroll
            for (int fm = 0; fm < 4; fm++) {
                int ki = (fm * 16 + l15) * FST + s * 16 + quad * 4;
                bf16x8 vkh = *(const bf16x8*)&Kh[ki];
                bf16x8 vkl = *(const bf16x8*)&Kl[ki];
                #pragma unroll
                for (int nf = 0; nf < 2; nf++) {
                    sacc[nf][fm] = __builtin_amdgcn_mfma_f32_16x16x32_bf16(vkh, vqh[nf], sacc[nf][fm], 0, 0, 0);
                    sacc[nf][fm] = __builtin_amdgcn_mfma_f32_16x16x32_bf16(vkh, vql[nf], sacc[nf][fm], 0, 0, 0);
                    sacc[nf][fm] = __builtin_amdgcn_mfma_f32_16x16x32_bf16(vkl, vqh[nf], sacc[nf][fm], 0, 0, 0);
                }
            }
        }

        // ---- online softmax per (lane, nf) ----
        #pragma unroll
        for (int nf = 0; nf < 2; nf++) {
            float p[4][4];
            float mt = -INFINITY;
            #pragma unroll
            for (int fm = 0; fm < 4; fm++)
                #pragma unroll
                for (int r = 0; r < 4; r++) {
                    p[fm][r] = sacc[nf][fm][r] * scale;
                    mt = fmaxf(mt, p[fm][r]);
                }
            mt = fmaxf(mt, __shfl_xor(mt, 16));
            mt = fmaxf(mt, __shfl_xor(mt, 32));
            float m_new = fmaxf(m_i[nf], mt);
            float alpha = __expf(m_i[nf] - m_new);
            float rs = 0.0f;
            #pragma unroll
            for (int fm = 0; fm < 4; fm++)
                #pragma unroll
                for (int r = 0; r < 4; r++) {
                    p[fm][r] = __expf(p[fm][r] - m_new);
                    rs += p[fm][r];
                }
            rs += __shfl_xor(rs, 16);
            rs += __shfl_xor(rs, 32);
            l_i[nf] = l_i[nf] * alpha + rs;
            m_i[nf] = m_new;
            #pragma unroll
            for (int fm = 0; fm < 4; fm++)
                #pragma unroll
                for (int e = 0; e < 4; e++) acc_o[nf][fm][e] *= alpha;

            // P -> LDS [qrow][key], wave-private rows
            int qrow = w * 32 + nf * 16 + l15;
            #pragma unroll
            for (int fm = 0; fm < 4; fm++) {
                uint32_t u0 = pack_bf16_rne(p[fm][0], p[fm][1]);
                uint32_t u1 = pack_bf16_rne(p[fm][2], p[fm][3]);
                *(uint2*)&Pt[qrow * FST + fm * 8 + quad * 2] = make_uint2(u0, u1);
            }
        }

        // ---- O^T += Vt · P^T ----
        #pragma unroll
        for (int s = 0; s < 2; s++) {
            bf16x8 pb[2];
            #pragma unroll
            for (int nf = 0; nf < 2; nf++)
                pb[nf] = *(const bf16x8*)&Pt[(w * 32 + nf * 16 + l15) * FST + s * 16 + quad * 4];
            #pragma unroll
            for (int fm = 0; fm < 4; fm++) {
                bf16x8 va = *(const bf16x8*)&Vt[(fm * 16 + l15) * FST + s * 16 + quad * 4];
                #pragma unroll
                for (int nf = 0; nf < 2; nf++)
                    acc_o[nf][fm] = __builtin_amdgcn_mfma_f32_16x16x32_bf16(va, pb[nf], acc_o[nf][fm], 0, 0, 0);
            }
        }
    }

    // ---- epilogue: write x pre-split bf16 ----
    #pragma unroll
    for (int nf = 0; nf < 2; nf++) {
        float rl = 1.0f / l_i[nf];
        size_t row = rowbase + qb * 128 + w * 32 + nf * 16 + l15;
        #pragma unroll
        for (int fm = 0; fm < 4; fm++) {
            int d0 = fm * 16 + quad * 4;
            uint32_t h0, l0, h1, l1;
            split2(acc_o[nf][fm][0] * rl, acc_o[nf][fm][1] * rl, h0, l0);
            split2(acc_o[nf][fm][2] * rl, acc_o[nf][fm][3] * rl, h1, l1);
            size_t wi = row * 512 + ((h * 64 + d0) >> 1);
            *(uint2*)&xhg[wi] = make_uint2(h0, h1);
            *(uint2*)&xlg[wi] = make_uint2(l0, l1);
        }
    }
}

extern "C" void kernel_launch(void* const* d_in, const int* in_sizes, int n_in,
                              void* d_out, int out_size, void* d_ws, size_t ws_size,
                              hipStream_t stream)
{
    const float* input_qv = (const float*)d_in[0];
    const float* input_k  = (const float*)d_in[1];
    const float* W_qv     = (const float*)d_in[2];
    const float* W_k      = (const float*)d_in[3];
    const float* W_proj   = (const float*)d_in[4];
    const float* b_proj   = (const float*)d_in[5];
    float* out = (float*)d_out;

    const int M = BATCH * SEQ;                       // 4096
    const size_t RW = 4096 * 512;                    // words per [M][1024-bf16] buffer

    uint32_t* qh = (uint32_t*)d_ws;                  // 5 RW buffers
    uint32_t* ql = qh + RW;
    uint32_t* vb = ql + RW;
    uint32_t* xh = vb + RW;
    uint32_t* xl = xh + RW;
    uint32_t* kh = (uint32_t*)d_out;                 // split K parked in d_out (16.8 MB);
    uint32_t* kl = kh + RW;                          // proj GEMM rewrites out afterwards

    uint32_t* w1h = xl + RW;                         // weight splits: 16.8 MB total
    uint32_t* w1l = w1h + 2048 * 512;
    uint32_t* w2h = w1l + 2048 * 512;
    uint32_t* w2l = w2h + 1024 * 512;
    uint32_t* w3h = w2l + 1024 * 512;
    uint32_t* w3l = w3h + 1024 * 512;

    const size_t wneed = (5 * RW + 2 * (2048 * 512) + 4 * (1024 * 512)) * 4;  // 58.7 MB
    dim3 blk(256);

    if (ws_size >= wneed) {
        // Buffer aliasing schedule (stream-ordered, all safe):
        //   ak (split input_k) parked in qh/ql  -> consumed by k-GEMM, then qv-GEMM overwrites
        //   aq (split input_qv) parked in xh/xl -> consumed by qv-GEMM, then flash overwrites
        convert_w<<<dim3(64, 16), blk, 0, stream>>>(W_qv, W_k, W_proj,
                                                    w1h, w1l, w2h, w2l, w3h, w3l);
        convert_in<<<dim3(4096), blk, 0, stream>>>(input_qv, input_k, xh, xl, qh, ql);
        // k projection first (reads ak from qh/ql slots)
        gemm_lds<1, 1, 2><<<dim3(8, 32), blk, 0, stream>>>(
            nullptr, qh, ql, nullptr, w2h, w2l,
            nullptr, nullptr, kh, kl, nullptr, M, 1024, 1024);
        // qv projection (reads aq from xh/xl slots; writes qh/ql/vb)
        gemm_lds<1, 1, 1><<<dim3(16, 32), blk, 0, stream>>>(
            nullptr, xh, xl, nullptr, w1h, w1l,
            nullptr, nullptr, qh, ql, vb, M, 2048, 1024);
        flash_attn<<<dim3(SEQ / 128, NH, BATCH), blk, 0, stream>>>(
            qh, ql, kh, kl, vb, xh, xl);
        gemm_lds<1, 1, 0><<<dim3(8, 32), blk, 0, stream>>>(
            nullptr, xh, xl, nullptr, w3h, w3l,
            b_proj, out, nullptr, nullptr, nullptr, M, 1024, 1024);
    } else {
        // fallback: fp32 operands, in-kernel split (needs only 5 RW = 41.9 MB)
        gemm_lds<0, 0, 1><<<dim3(16, 32), blk, 0, stream>>>(
            input_qv, nullptr, nullptr, W_qv, nullptr, nullptr,
            nullptr, nullptr, qh, ql, vb, M, 2048, 1024);
        gemm_lds<0, 0, 2><<<dim3(8, 32), blk, 0, stream>>>(
            input_k, nullptr, nullptr, W_k, nullptr, nullptr,
            nullptr, nullptr, kh, kl, nullptr, M, 1024, 1024);
        flash_attn<<<dim3(SEQ / 128, NH, BATCH), blk, 0, stream>>>(
            qh, ql, kh, kl, vb, xh, xl);
        gemm_lds<0, 0, 0><<<dim3(8, 32), blk, 0, stream>>>(
            nullptr, xh, xl, W_proj, nullptr, nullptr,
            b_proj, out, nullptr, nullptr, nullptr, M, 1024, 1024);
    }
}